// Round 19
// baseline (313.565 us; speedup 1.0000x reference)
//
#include <hip/hip_runtime.h>

#define NN 8
#define HH 512
#define WW 512
#define CC 3
#define KK 5
#define PADP 2
#define WROWF (WW * CC)          // 1536 floats per image row
#define NBLOCKS 4096             // (n, h-pair, half-row walk): 8 * 256 * 2

typedef float f4a __attribute__((ext_vector_type(4), aligned(4)));

struct Row { f4a L0, L1, L2, L3; };   // 15-float window f0..f14 (L3 overlaps at f11)

__device__ __forceinline__ void load_row(const float* rb, Row& r) {
    r.L0 = *(const f4a*)(rb);
    r.L1 = *(const f4a*)(rb + 4);
    r.L2 = *(const f4a*)(rb + 8);
    r.L3 = *(const f4a*)(rb + 11);
}

// All weight accesses are textual constant indices into a local array:
// no pointer is ever formed -> arrays stay in registers (rule #20 safe).
#define FMA5(R, W, base, a0, a1, a2) do {                                \
    const float _q0 = W[(base) + 0], _q1 = W[(base) + 1];                \
    const float _q2 = W[(base) + 2], _q3 = W[(base) + 3];                \
    const float _q4 = W[(base) + 4];                                     \
    a0 = fmaf((R).L0[0], _q0, a0); a1 = fmaf((R).L0[1], _q0, a1); a2 = fmaf((R).L0[2], _q0, a2); \
    a0 = fmaf((R).L0[3], _q1, a0); a1 = fmaf((R).L1[0], _q1, a1); a2 = fmaf((R).L1[1], _q1, a2); \
    a0 = fmaf((R).L1[2], _q2, a0); a1 = fmaf((R).L1[3], _q2, a1); a2 = fmaf((R).L2[0], _q2, a2); \
    a0 = fmaf((R).L2[1], _q3, a0); a1 = fmaf((R).L2[2], _q3, a1); a2 = fmaf((R).L2[3], _q3, a2); \
    a0 = fmaf((R).L3[1], _q4, a0); a1 = fmaf((R).L3[2], _q4, a1); a2 = fmaf((R).L3[3], _q4, a2); \
} while (0)

#define GLDS16(gp, lp) __builtin_amdgcn_global_load_lds( \
    (const __attribute__((address_space(1))) void*)(gp), \
    (__attribute__((address_space(3))) void*)(lp), 16, 0, 0)
#define GLDS4(gp, lp) __builtin_amdgcn_global_load_lds( \
    (const __attribute__((address_space(1))) void*)(gp), \
    (__attribute__((address_space(3))) void*)(lp), 4, 0, 0)

// stage both rows' weights for wseg index jj into the LDS buffer pair: 14 VMEM ops
#define STAGE2(jj) do {                                                  \
    const long _p = (long)(nHH + h0) * WW + (((half << 2) | (jj)) << 6); \
    const char* _s0 = (const char*)(wt + _p * (KK * KK));                \
    const char* _s1 = (const char*)(wt + (_p + WW) * (KK * KK));         \
    _Pragma("unroll")                                                    \
    for (int _it = 0; _it < 6; ++_it)                                    \
        GLDS16(_s0 + _it * 1024 + lane * 16, wldsA + _it * 256);         \
    GLDS4(_s0 + 6144 + lane * 4, wldsA + 1536);                          \
    _Pragma("unroll")                                                    \
    for (int _it = 0; _it < 6; ++_it)                                    \
        GLDS16(_s1 + _it * 1024 + lane * 16, wldsB + _it * 256);         \
    GLDS4(_s1 + 6144 + lane * 4, wldsB + 1536);                          \
} while (0)

__global__ __launch_bounds__(64, 3) void conv_local_kernel(
    const float* __restrict__ in,   // (N,H,W,C)
    const float* __restrict__ wt,   // (N,H,W,25)
    float* __restrict__ out)        // (N,H,W,C)
{
    __shared__ float wldsA[64 * KK * KK];   // 6.4 KB: row h0 weights
    __shared__ float wldsB[64 * KK * KK];   // 6.4 KB: row h0+1 weights

    const int lane = threadIdx.x;
    // bijective XCD swizzle: 4096 = 8 x 512; XCD k streams image k only
    const int b    = ((blockIdx.x & 7) << 9) | (blockIdx.x >> 3);
    const int n    = b >> 9;
    const int rem  = b & 511;
    const int hp   = rem >> 1;         // 0..255
    const int half = rem & 1;          // walks wseg half*4 .. half*4+3
    const int h0   = hp << 1;          // 0..510 (rows h0, h0+1)
    const int nHH  = n * HH;

    const float* inb  = in + (size_t)n * (HH * WW * CC);
    const bool  rowok = (hp >= 1) && (hp <= 254);   // h0-2 >= 0 && h0+4 <= 511

    STAGE2(0);                          // prologue: step-0 weights in flight

#pragma unroll 1
    for (int j = 0; j < 4; ++j) {
        const int  w0 = (((half << 2) | j)) << 6;
        const long p0 = (long)(nHH + h0) * WW + w0;
        const long p1 = p0 + WW;
        const bool fast = rowok && (w0 != 0) && (w0 != WW - 64);

        Row R0, R1, R2, R3, R4, R5;
        if (fast) {
            // inputs issued before the drain: latency overlaps the weight wait
            const float* rb = inb + ((long)(h0 - PADP) * WW + (w0 + lane - PADP)) * CC;
            load_row(rb + 0 * WROWF, R0);
            load_row(rb + 1 * WROWF, R1);
            load_row(rb + 2 * WROWF, R2);
            load_row(rb + 3 * WROWF, R3);
            load_row(rb + 4 * WROWF, R4);
            load_row(rb + 5 * WROWF, R5);
        }
        asm volatile("s_waitcnt vmcnt(0)" ::: "memory");   // weights j + inputs done
        __builtin_amdgcn_sched_barrier(0);

        // ---- hoist weights LDS -> registers (constant indices, no pointers) ----
        float wA[KK * KK], wB[KK * KK];
#pragma unroll
        for (int k = 0; k < KK * KK; ++k) wA[k] = wldsA[lane * (KK * KK) + k];
#pragma unroll
        for (int k = 0; k < KK * KK; ++k) wB[k] = wldsB[lane * (KK * KK) + k];
        // ds_reads complete -> buffers are free to overwrite
        asm volatile("s_waitcnt lgkmcnt(0)" ::: "memory");
        __builtin_amdgcn_sched_barrier(0);

        if (j < 3) STAGE2(j + 1);       // next step's weights stream DURING compute

        if (fast) {
            float a0 = 0.f, a1 = 0.f, a2 = 0.f;   // px (h0,   w)
            float c0 = 0.f, c1 = 0.f, c2 = 0.f;   // px (h0+1, w)
            FMA5(R0, wA, 0,  a0, a1, a2);
            FMA5(R1, wA, 5,  a0, a1, a2);
            FMA5(R1, wB, 0,  c0, c1, c2);
            FMA5(R2, wA, 10, a0, a1, a2);
            FMA5(R2, wB, 5,  c0, c1, c2);
            FMA5(R3, wA, 15, a0, a1, a2);
            FMA5(R3, wB, 10, c0, c1, c2);
            FMA5(R4, wA, 20, a0, a1, a2);
            FMA5(R4, wB, 15, c0, c1, c2);
            FMA5(R5, wB, 20, c0, c1, c2);

            float* o0 = out + (p0 + lane) * CC;
            o0[0] = a0; o0[1] = a1; o0[2] = a2;
            float* o1 = out + (p1 + lane) * CC;
            o1[0] = c0; o1[1] = c1; o1[2] = c2;
        } else {
            // border step: predicated scalar path; both rows in one constant-index loop
            const int w = w0 + lane;
            float a0 = 0.f, a1 = 0.f, a2 = 0.f;   // px (h0,   w)
            float c0 = 0.f, c1 = 0.f, c2 = 0.f;   // px (h0+1, w)
#pragma unroll
            for (int dh = 0; dh < KK; ++dh) {
                const int iha = h0 + dh - PADP;
                const int ihc = iha + 1;
                const bool roka = ((unsigned)iha < (unsigned)HH);
                const bool rokc = ((unsigned)ihc < (unsigned)HH);
#pragma unroll
                for (int dw = 0; dw < KK; ++dw) {
                    const int iw = w + dw - PADP;
                    const bool cok = ((unsigned)iw < (unsigned)WW);
                    const float* pa = inb + ((long)(iha * WW + iw)) * CC;
                    const float* pc = inb + ((long)(ihc * WW + iw)) * CC;
                    const bool oka = roka && cok;
                    const bool okc = rokc && cok;
                    float va0 = oka ? pa[0] : 0.f;
                    float va1 = oka ? pa[1] : 0.f;
                    float va2 = oka ? pa[2] : 0.f;
                    float vc0 = okc ? pc[0] : 0.f;
                    float vc1 = okc ? pc[1] : 0.f;
                    float vc2 = okc ? pc[2] : 0.f;
                    const float wva = wA[dh * KK + dw];   // constant index
                    const float wvc = wB[dh * KK + dw];   // constant index
                    a0 = fmaf(va0, wva, a0);
                    a1 = fmaf(va1, wva, a1);
                    a2 = fmaf(va2, wva, a2);
                    c0 = fmaf(vc0, wvc, c0);
                    c1 = fmaf(vc1, wvc, c1);
                    c2 = fmaf(vc2, wvc, c2);
                }
            }
            float* o0 = out + (p0 + lane) * CC;
            o0[0] = a0; o0[1] = a1; o0[2] = a2;
            float* o1 = out + (p1 + lane) * CC;
            o1[0] = c0; o1[1] = c1; o1[2] = c2;
        }
    }
}

extern "C" void kernel_launch(void* const* d_in, const int* in_sizes, int n_in,
                              void* d_out, int out_size, void* d_ws, size_t ws_size,
                              hipStream_t stream) {
    const float* in = (const float*)d_in[0];   // (8,512,512,3) f32
    const float* wt = (const float*)d_in[1];   // (8,512,512,25) f32
    float* out = (float*)d_out;                // (8,512,512,3) f32

    conv_local_kernel<<<NBLOCKS, 64, 0, stream>>>(in, wt, out);
}

// Round 20
// 56.473 us; speedup vs baseline: 5.5525x; 5.5525x over previous
//
#include <hip/hip_runtime.h>

#define NN 8
#define HH 512
#define WW 512
#define CC 3
#define KK 5
#define PADP 2
#define WROWF (WW * CC)          // 1536 floats per image row
#define NBLOCKS 4096             // (n, h-pair, half-row walk): 8 * 256 * 2

typedef float f4a __attribute__((ext_vector_type(4), aligned(4)));

struct Row { f4a L0, L1, L2, L3; };   // 15-float window f0..f14 (L3 overlaps at f11)

__device__ __forceinline__ void load_row(const float* rb, Row& r) {
    r.L0 = *(const f4a*)(rb);
    r.L1 = *(const f4a*)(rb + 4);
    r.L2 = *(const f4a*)(rb + 8);
    r.L3 = *(const f4a*)(rb + 11);
}

__device__ __forceinline__ void fma_row(const Row& r, const float* wp,
                                        float& a0, float& a1, float& a2) {
    const float w0 = wp[0], w1 = wp[1], w2 = wp[2], w3 = wp[3], w4 = wp[4];
    a0 = fmaf(r.L0[0], w0, a0); a1 = fmaf(r.L0[1], w0, a1); a2 = fmaf(r.L0[2], w0, a2);
    a0 = fmaf(r.L0[3], w1, a0); a1 = fmaf(r.L1[0], w1, a1); a2 = fmaf(r.L1[1], w1, a2);
    a0 = fmaf(r.L1[2], w2, a0); a1 = fmaf(r.L1[3], w2, a1); a2 = fmaf(r.L2[0], w2, a2);
    a0 = fmaf(r.L2[1], w3, a0); a1 = fmaf(r.L2[2], w3, a1); a2 = fmaf(r.L2[3], w3, a2);
    a0 = fmaf(r.L3[1], w4, a0); a1 = fmaf(r.L3[2], w4, a1); a2 = fmaf(r.L3[3], w4, a2);
}

#define GLDS16(gp, lp) __builtin_amdgcn_global_load_lds( \
    (const __attribute__((address_space(1))) void*)(gp), \
    (__attribute__((address_space(3))) void*)(lp), 16, 0, 0)
#define GLDS4(gp, lp) __builtin_amdgcn_global_load_lds( \
    (const __attribute__((address_space(1))) void*)(gp), \
    (__attribute__((address_space(3))) void*)(lp), 4, 0, 0)

__global__ __launch_bounds__(64, 4) void conv_local_kernel(
    const float* __restrict__ in,   // (N,H,W,C)
    const float* __restrict__ wt,   // (N,H,W,25)
    float* __restrict__ out)        // (N,H,W,C)
{
    __shared__ float wldsA[64 * KK * KK];   // 6.4 KB: row h0 weights
    __shared__ float wldsB[64 * KK * KK];   // 6.4 KB: row h0+1 weights

    const int lane = threadIdx.x;
    // bijective XCD swizzle: 4096 = 8 x 512; XCD k streams image k only
    const int b    = ((blockIdx.x & 7) << 9) | (blockIdx.x >> 3);
    const int n    = b >> 9;
    const int rem  = b & 511;
    const int hp   = rem >> 1;         // 0..255
    const int half = rem & 1;          // walks wseg half*4 .. half*4+3
    const int h0   = hp << 1;          // 0..510 (rows h0, h0+1)
    const int nHH  = n * HH;

    const float* inb  = in + (size_t)n * (HH * WW * CC);
    const bool  rowok = (hp >= 1) && (hp <= 254);   // h0-2 >= 0 && h0+4 <= 511

#pragma unroll 1
    for (int j = 0; j < 4; ++j) {
        const int  w0 = (((half << 2) | j)) << 6;   // contiguous weight walk
        const long p0 = (long)(nHH + h0) * WW + w0;
        const long p1 = p0 + WW;

        // previous step's ds_reads are complete (results consumed); belt-and-braces:
        asm volatile("s_waitcnt lgkmcnt(0)" ::: "memory");

        // ---- stage both rows' weights: 14 async GLDS ops, two contiguous streams ----
        {
            const char* s0 = (const char*)(wt + p0 * (KK * KK));
            const char* s1 = (const char*)(wt + p1 * (KK * KK));
#pragma unroll
            for (int it = 0; it < 6; ++it)
                GLDS16(s0 + it * 1024 + lane * 16, wldsA + it * 256);
            GLDS4(s0 + 6144 + lane * 4, wldsA + 1536);
#pragma unroll
            for (int it = 0; it < 6; ++it)
                GLDS16(s1 + it * 1024 + lane * 16, wldsB + it * 256);
            GLDS4(s1 + 6144 + lane * 4, wldsB + 1536);
        }

        const float* wp0 = &wldsA[lane * (KK * KK)];
        const float* wp1 = &wldsB[lane * (KK * KK)];
        const bool fast = rowok && (w0 != 0) && (w0 != WW - 64);

        if (fast) {
            // 6 input rows h0-2 .. h0+3 upfront (L2-hot; latency hides under wt drain)
            const float* rb = inb + ((long)(h0 - PADP) * WW + (w0 + lane - PADP)) * CC;
            Row R0, R1, R2, R3, R4, R5;
            load_row(rb + 0 * WROWF, R0);
            load_row(rb + 1 * WROWF, R1);
            load_row(rb + 2 * WROWF, R2);
            load_row(rb + 3 * WROWF, R3);
            load_row(rb + 4 * WROWF, R4);
            load_row(rb + 5 * WROWF, R5);
            asm volatile("s_waitcnt vmcnt(0)" ::: "memory");
            __builtin_amdgcn_sched_barrier(0);

            // independent single-wave blocks at staggered phases: setprio lets the
            // compute-phase wave win VALU arbitration over issue-phase waves (T5)
            __builtin_amdgcn_s_setprio(1);
            float a0 = 0.f, a1 = 0.f, a2 = 0.f;   // px (h0,   w)
            float c0 = 0.f, c1 = 0.f, c2 = 0.f;   // px (h0+1, w)
            fma_row(R0, wp0 + 0,  a0, a1, a2);
            fma_row(R1, wp0 + 5,  a0, a1, a2);
            fma_row(R1, wp1 + 0,  c0, c1, c2);
            fma_row(R2, wp0 + 10, a0, a1, a2);
            fma_row(R2, wp1 + 5,  c0, c1, c2);
            fma_row(R3, wp0 + 15, a0, a1, a2);
            fma_row(R3, wp1 + 10, c0, c1, c2);
            fma_row(R4, wp0 + 20, a0, a1, a2);
            fma_row(R4, wp1 + 15, c0, c1, c2);
            fma_row(R5, wp1 + 20, c0, c1, c2);
            __builtin_amdgcn_s_setprio(0);

            float* o0 = out + (p0 + lane) * CC;
            o0[0] = a0; o0[1] = a1; o0[2] = a2;
            float* o1 = out + (p1 + lane) * CC;
            o1[0] = c0; o1[1] = c1; o1[2] = c2;
        } else {
            asm volatile("s_waitcnt vmcnt(0)" ::: "memory");
            __builtin_amdgcn_sched_barrier(0);
            // border step: predicated scalar path (R1-proven), weights from LDS
#pragma unroll
            for (int px = 0; px < 2; ++px) {
                const int hh = h0 + px;
                const int w  = w0 + lane;
                const float* wp = px ? wp1 : wp0;
                float a0 = 0.f, a1 = 0.f, a2 = 0.f;
#pragma unroll
                for (int dh = 0; dh < KK; ++dh) {
                    const int ih = hh + dh - PADP;
                    const bool rok = ((unsigned)ih < (unsigned)HH);
#pragma unroll
                    for (int dw = 0; dw < KK; ++dw) {
                        const int iw = w + dw - PADP;
                        const bool ok = rok && ((unsigned)iw < (unsigned)WW);
                        const float* p = inb + ((long)(ih * WW + iw)) * CC;
                        float v0 = ok ? p[0] : 0.f;
                        float v1 = ok ? p[1] : 0.f;
                        float v2 = ok ? p[2] : 0.f;
                        const float wv = wp[dh * KK + dw];
                        a0 = fmaf(v0, wv, a0);
                        a1 = fmaf(v1, wv, a1);
                        a2 = fmaf(v2, wv, a2);
                    }
                }
                float* o = out + ((long)(nHH + hh) * WW + w) * CC;
                o[0] = a0; o[1] = a1; o[2] = a2;
            }
        }
    }
}

extern "C" void kernel_launch(void* const* d_in, const int* in_sizes, int n_in,
                              void* d_out, int out_size, void* d_ws, size_t ws_size,
                              hipStream_t stream) {
    const float* in = (const float*)d_in[0];   // (8,512,512,3) f32
    const float* wt = (const float*)d_in[1];   // (8,512,512,25) f32
    float* out = (float*)d_out;                // (8,512,512,3) f32

    conv_local_kernel<<<NBLOCKS, 64, 0, stream>>>(in, wt, out);
}